// Round 1
// baseline (268.974 us; speedup 1.0000x reference)
//
#include <hip/hip_runtime.h>
#include <hip/hip_bf16.h>
#include <math.h>

typedef __bf16 bf16;
typedef __attribute__((ext_vector_type(8))) __bf16 bf16x8;
typedef __attribute__((ext_vector_type(4))) __bf16 bf16x4;
typedef __attribute__((ext_vector_type(4))) float f32x4;

#define EPSBN 1e-5f
#define B_    4096
#define N_    64
#define FIN_  67
#define E_    512
#define NSLOT 128

// ---------------- K0: dense normalized adjacency (bf16 hi/lo) + padded weights + zero partials ----
// An[d][s] = sum over edges (s->d, incl self loop, incl duplicates) of dinv[s]*dinv[d]
__global__ __launch_bounds__(256) void k0_prep(const int* __restrict__ edge,
    const float* __restrict__ W1, const float* __restrict__ W2,
    float* __restrict__ partials,          // NSLOT*64*2 * 2 layers, contiguous
    bf16* __restrict__ an_hi, bf16* __restrict__ an_lo,
    bf16* __restrict__ wpad,               // [64][104] bf16, K padded 67->104-pitch (zeros >=67)
    bf16* __restrict__ w2pad)              // [32][72]  bf16, K=64, pitch 72 (zeros >=64)
{
    int tid = threadIdx.x;
    for (int i = blockIdx.x * 256 + tid; i < NSLOT * 64 * 4; i += gridDim.x * 256)
        partials[i] = 0.f;
    if (blockIdx.x == 1) {
        for (int i = tid; i < 64 * 104; i += 256) {
            int n = i / 104, f = i % 104;
            wpad[i] = (f < FIN_) ? (bf16)W1[n * FIN_ + f] : (bf16)0.f;
        }
        return;
    }
    if (blockIdx.x == 2) {
        for (int i = tid; i < 32 * 72; i += 256) {
            int o = i / 72, f = i % 72;
            w2pad[i] = (f < 64) ? (bf16)W2[o * 64 + f] : (bf16)0.f;
        }
        return;
    }
    if (blockIdx.x != 0) return;

    __shared__ float An[64 * 64];
    __shared__ int ssrc[E_], sdst[E_];
    __shared__ int deg[N_];
    __shared__ float dinv[N_];
    for (int i = tid; i < 64 * 64; i += 256) An[i] = 0.f;
    for (int i = tid; i < E_; i += 256) { ssrc[i] = edge[i]; sdst[i] = edge[E_ + i]; }
    if (tid < N_) deg[tid] = 1;                       // self loop contributes 1
    __syncthreads();
    for (int i = tid; i < E_; i += 256) atomicAdd(&deg[sdst[i]], 1);
    __syncthreads();
    if (tid < N_) dinv[tid] = rsqrtf((float)deg[tid]);
    __syncthreads();
    for (int i = tid; i < E_; i += 256) {
        int s = ssrc[i], d = sdst[i];
        atomicAdd(&An[d * 64 + s], dinv[s] * dinv[d]);   // duplicates accumulate, like scatter-add
    }
    if (tid < N_) atomicAdd(&An[tid * 64 + tid], dinv[tid] * dinv[tid]);  // self loop
    __syncthreads();
    for (int i = tid; i < 64 * 64; i += 256) {
        float v = An[i];
        bf16 h = (bf16)v;
        an_hi[i] = h;
        an_lo[i] = (bf16)(v - (float)h);              // exact residual (Sterbenz), bf16-rounded
    }
}

// ---------------- K1: GCN layer 1, fully-MFMA: h = x@W1^T ; out = An@h ; bias+stats ----------------
__global__ __launch_bounds__(256) void k1_gcn1(
    const float* __restrict__ x,          // [B][64][67]
    const float* __restrict__ b1,
    const bf16* __restrict__ an_hi, const bf16* __restrict__ an_lo,
    const bf16* __restrict__ wpad,        // [64][104] bf16
    bf16* __restrict__ g1out,             // [B][64][64]
    float* __restrict__ part1)            // [NSLOT][64][2]
{
    __shared__ union {
        struct { float xraw[4352]; bf16 wb[64 * 104]; } s0;               // 17408 + 13312 B
        struct { bf16 hhi[64 * 72]; bf16 hlo[64 * 72]; bf16 ost[64 * 72]; } s1;  // 27648 B
    } u;
    int tid = threadIdx.x, b = blockIdx.x;
    int w = tid >> 6, lane = tid & 63, q = lane >> 4, r15 = lane & 15;
    int arow = w * 16 + r15;

    // An fragments live in registers (same 16 KB for every block -> L2/L3-hot)
    const bf16* ahp = an_hi + arow * 64 + q * 8;
    const bf16* alp = an_lo + arow * 64 + q * 8;
    bf16x8 Ah0 = *(const bf16x8*)ahp;
    bf16x8 Ah1 = *(const bf16x8*)(ahp + 32);
    bf16x8 Al0 = *(const bf16x8*)alp;
    bf16x8 Al1 = *(const bf16x8*)(alp + 32);

    // stage x raw f32 (vectorized, no per-element conversion) + prepadded W1 bf16
    const f32x4* xb4 = (const f32x4*)(x + (size_t)b * (N_ * FIN_));       // 4288 f32, 16B aligned
    f32x4* xl4 = (f32x4*)u.s0.xraw;
    for (int i = tid; i < 1072; i += 256) xl4[i] = xb4[i];
    const bf16x8* wg8 = (const bf16x8*)wpad;
    bf16x8* wl8 = (bf16x8*)u.s0.wb;
    for (int i = tid; i < 832; i += 256) wl8[i] = wg8[i];
    __syncthreads();

    // MFMA1: h[n][c] = sum_k x[n][k]*W1[c][k]  (A-frag built per-lane straight from raw f32)
    f32x4 z4 = {0.f, 0.f, 0.f, 0.f};
    f32x4 acc[4] = {z4, z4, z4, z4};
    const float* xr = u.s0.xraw + arow * FIN_;
#pragma unroll
    for (int kt = 0; kt < 3; ++kt) {
        bf16x8 a;
        int k0 = kt * 32 + q * 8;
#pragma unroll
        for (int j = 0; j < 8; ++j) {
            int k = k0 + j;
            a[j] = (k < FIN_) ? (bf16)xr[k] : (bf16)0.f;
        }
#pragma unroll
        for (int nt = 0; nt < 4; ++nt) {
            bf16x8 bb = *(const bf16x8*)&u.s0.wb[(nt * 16 + r15) * 104 + k0];
            acc[nt] = __builtin_amdgcn_mfma_f32_16x16x32_bf16(a, bb, acc[nt], 0, 0, 0);
        }
    }
    __syncthreads();                                  // xraw/wb dead; s1 overlays s0

    // write h^T as bf16 hi/lo pair: hT[c][s], s = node = output row of MFMA1
    int sbase = w * 16 + q * 4;
#pragma unroll
    for (int nt = 0; nt < 4; ++nt) {
        int c = nt * 16 + r15;
        bf16x4 hi, lo;
#pragma unroll
        for (int r = 0; r < 4; ++r) {
            float v = acc[nt][r];
            bf16 h = (bf16)v;
            hi[r] = h;
            lo[r] = (bf16)(v - (float)h);
        }
        *(bf16x4*)&u.s1.hhi[c * 72 + sbase] = hi;
        *(bf16x4*)&u.s1.hlo[c * 72 + sbase] = lo;
    }
    __syncthreads();

    // MFMA2: out[d][c] = sum_s An[d][s]*h[s][c]  via An_hi@(Hh+Hl) + An_lo@Hh
    f32x4 acc2[4] = {z4, z4, z4, z4};
#pragma unroll
    for (int kt = 0; kt < 2; ++kt) {
        bf16x8 Ahk = kt ? Ah1 : Ah0;
        bf16x8 Alk = kt ? Al1 : Al0;
#pragma unroll
        for (int nt = 0; nt < 4; ++nt) {
            int o = (nt * 16 + r15) * 72 + kt * 32 + q * 8;
            bf16x8 Hh = *(const bf16x8*)&u.s1.hhi[o];
            bf16x8 Hl = *(const bf16x8*)&u.s1.hlo[o];
            acc2[nt] = __builtin_amdgcn_mfma_f32_16x16x32_bf16(Ahk, Hh, acc2[nt], 0, 0, 0);
            acc2[nt] = __builtin_amdgcn_mfma_f32_16x16x32_bf16(Ahk, Hl, acc2[nt], 0, 0, 0);
            acc2[nt] = __builtin_amdgcn_mfma_f32_16x16x32_bf16(Alk, Hh, acc2[nt], 0, 0, 0);
        }
    }

    // epilogue: bias, per-node stats, bf16 store staged through LDS for coalescing
    float rs1[4] = {0.f, 0.f, 0.f, 0.f}, rs2[4] = {0.f, 0.f, 0.f, 0.f};
#pragma unroll
    for (int nt = 0; nt < 4; ++nt) {
        int c = nt * 16 + r15;
        float bc = b1[c];
#pragma unroll
        for (int r = 0; r < 4; ++r) {
            float v = acc2[nt][r] + bc;
            rs1[r] += v; rs2[r] += v * v;
            u.s1.ost[(w * 16 + q * 4 + r) * 72 + c] = (bf16)v;
        }
    }
#pragma unroll
    for (int r = 0; r < 4; ++r)
#pragma unroll
        for (int o = 1; o < 16; o <<= 1) {
            rs1[r] += __shfl_xor(rs1[r], o);
            rs2[r] += __shfl_xor(rs2[r], o);
        }
    if (r15 == 0) {
        int slot = b & (NSLOT - 1);
#pragma unroll
        for (int r = 0; r < 4; ++r) {
            int d = w * 16 + q * 4 + r;
            atomicAdd(&part1[(slot * 64 + d) * 2 + 0], rs1[r]);
            atomicAdd(&part1[(slot * 64 + d) * 2 + 1], rs2[r]);
        }
    }
    __syncthreads();
    int n = tid >> 2, oq = tid & 3;
    bf16x8 o0 = *(const bf16x8*)&u.s1.ost[n * 72 + oq * 16];
    bf16x8 o1 = *(const bf16x8*)&u.s1.ost[n * 72 + oq * 16 + 8];
    bf16* gp = g1out + ((size_t)b * 4096 + n * 64 + oq * 16);
    *(bf16x8*)gp = o0;
    *(bf16x8*)(gp + 8) = o1;
}

// ---------------- BN stats reduce: partials -> scale/shift per node ----------------
__global__ __launch_bounds__(64) void k_bnstats(
    const float* __restrict__ part,       // [NSLOT][64][2]
    const float* __restrict__ gamma, const float* __restrict__ beta,
    float* __restrict__ scale, float* __restrict__ shift, float inv_count)
{
    int n = blockIdx.x, t = threadIdx.x;
    float s1 = part[(t * 64 + n) * 2] + part[((t + 64) * 64 + n) * 2];
    float s2 = part[(t * 64 + n) * 2 + 1] + part[((t + 64) * 64 + n) * 2 + 1];
#pragma unroll
    for (int o = 32; o > 0; o >>= 1) { s1 += __shfl_down(s1, o); s2 += __shfl_down(s2, o); }
    if (t == 0) {
        float mean = s1 * inv_count;
        float var = s2 * inv_count - mean * mean;
        float sc = gamma[n] * rsqrtf(var + EPSBN);
        scale[n] = sc;
        shift[n] = beta[n] - mean * sc;
    }
}

// ---------------- K3: BN1+relu fused into A-frag -> GCN layer 2 (MFMA x2) -> stats ----------------
__global__ __launch_bounds__(256) void k3_gcn2(
    const bf16* __restrict__ g1out,       // [B][64][64]
    const float* __restrict__ b2,
    const float* __restrict__ scale1, const float* __restrict__ shift1,
    const bf16* __restrict__ an_hi, const bf16* __restrict__ an_lo,
    const bf16* __restrict__ w2pad,       // [32][72] bf16
    bf16* __restrict__ g2out,             // [B][64][32]
    float* __restrict__ part2)
{
    __shared__ union {
        struct { bf16 graw[4096]; bf16 wb[32 * 72]; } s0;                 // 8192 + 4608 B
        struct { bf16 hhi[32 * 72]; bf16 hlo[32 * 72]; bf16 ost[64 * 40]; } s1;  // 14336 B
    } u;
    int tid = threadIdx.x, b = blockIdx.x;
    int w = tid >> 6, lane = tid & 63, q = lane >> 4, r15 = lane & 15;
    int arow = w * 16 + r15;

    const bf16* ahp = an_hi + arow * 64 + q * 8;
    const bf16* alp = an_lo + arow * 64 + q * 8;
    bf16x8 Ah0 = *(const bf16x8*)ahp;
    bf16x8 Ah1 = *(const bf16x8*)(ahp + 32);
    bf16x8 Al0 = *(const bf16x8*)alp;
    bf16x8 Al1 = *(const bf16x8*)(alp + 32);
    float sc = scale1[arow], sh = shift1[arow];       // per-node BN affine (row-uniform per lane)

    const bf16x8* gg8 = (const bf16x8*)(g1out + (size_t)b * 4096);
    bf16x8* gl8 = (bf16x8*)u.s0.graw;
    for (int i = tid; i < 512; i += 256) gl8[i] = gg8[i];
    const bf16x8* wg8 = (const bf16x8*)w2pad;
    bf16x8* wl8 = (bf16x8*)u.s0.wb;
    for (int i = tid; i < 288; i += 256) wl8[i] = wg8[i];
    __syncthreads();

    // MFMA1: h[n][o] = sum_c relu(sc[n]*g1[n][c]+sh[n]) * W2[o][c]
    f32x4 z4 = {0.f, 0.f, 0.f, 0.f};
    f32x4 acc[2] = {z4, z4};
#pragma unroll
    for (int kt = 0; kt < 2; ++kt) {
        int k0 = kt * 32 + q * 8;
        bf16x8 raw = *(const bf16x8*)&u.s0.graw[arow * 64 + k0];
        bf16x8 a;
#pragma unroll
        for (int j = 0; j < 8; ++j)
            a[j] = (bf16)fmaxf(fmaf(sc, (float)raw[j], sh), 0.f);
#pragma unroll
        for (int nt = 0; nt < 2; ++nt) {
            bf16x8 bb = *(const bf16x8*)&u.s0.wb[(nt * 16 + r15) * 72 + k0];
            acc[nt] = __builtin_amdgcn_mfma_f32_16x16x32_bf16(a, bb, acc[nt], 0, 0, 0);
        }
    }
    __syncthreads();

    int sbase = w * 16 + q * 4;
#pragma unroll
    for (int nt = 0; nt < 2; ++nt) {
        int c = nt * 16 + r15;
        bf16x4 hi, lo;
#pragma unroll
        for (int r = 0; r < 4; ++r) {
            float v = acc[nt][r];
            bf16 h = (bf16)v;
            hi[r] = h;
            lo[r] = (bf16)(v - (float)h);
        }
        *(bf16x4*)&u.s1.hhi[c * 72 + sbase] = hi;
        *(bf16x4*)&u.s1.hlo[c * 72 + sbase] = lo;
    }
    __syncthreads();

    f32x4 acc2[2] = {z4, z4};
#pragma unroll
    for (int kt = 0; kt < 2; ++kt) {
        bf16x8 Ahk = kt ? Ah1 : Ah0;
        bf16x8 Alk = kt ? Al1 : Al0;
#pragma unroll
        for (int nt = 0; nt < 2; ++nt) {
            int o = (nt * 16 + r15) * 72 + kt * 32 + q * 8;
            bf16x8 Hh = *(const bf16x8*)&u.s1.hhi[o];
            bf16x8 Hl = *(const bf16x8*)&u.s1.hlo[o];
            acc2[nt] = __builtin_amdgcn_mfma_f32_16x16x32_bf16(Ahk, Hh, acc2[nt], 0, 0, 0);
            acc2[nt] = __builtin_amdgcn_mfma_f32_16x16x32_bf16(Ahk, Hl, acc2[nt], 0, 0, 0);
            acc2[nt] = __builtin_amdgcn_mfma_f32_16x16x32_bf16(Alk, Hh, acc2[nt], 0, 0, 0);
        }
    }

    float rs1[4] = {0.f, 0.f, 0.f, 0.f}, rs2[4] = {0.f, 0.f, 0.f, 0.f};
#pragma unroll
    for (int nt = 0; nt < 2; ++nt) {
        int c = nt * 16 + r15;
        float bc = b2[c];
#pragma unroll
        for (int r = 0; r < 4; ++r) {
            float v = acc2[nt][r] + bc;
            rs1[r] += v; rs2[r] += v * v;
            u.s1.ost[(w * 16 + q * 4 + r) * 40 + c] = (bf16)v;
        }
    }
#pragma unroll
    for (int r = 0; r < 4; ++r)
#pragma unroll
        for (int o = 1; o < 16; o <<= 1) {
            rs1[r] += __shfl_xor(rs1[r], o);
            rs2[r] += __shfl_xor(rs2[r], o);
        }
    if (r15 == 0) {
        int slot = b & (NSLOT - 1);
#pragma unroll
        for (int r = 0; r < 4; ++r) {
            int d = w * 16 + q * 4 + r;
            atomicAdd(&part2[(slot * 64 + d) * 2 + 0], rs1[r]);
            atomicAdd(&part2[(slot * 64 + d) * 2 + 1], rs2[r]);
        }
    }
    __syncthreads();
    int n = tid >> 2, oq = tid & 3;
    bf16x8 ov = *(const bf16x8*)&u.s1.ost[n * 40 + oq * 8];
    *(bf16x8*)(g2out + ((size_t)b * 2048 + n * 32 + oq * 8)) = ov;
}

// ---------------- K6: MLP1 split-K GEMM, register-prefetch pipeline ----------------
// grid (64 m-tiles, 7 n-tiles, 4 k-splits) = 1792 blocks; partials fp32.
__global__ __launch_bounds__(256) void k6_mlp1(
    const float* __restrict__ A,          // [4096][2048]
    const float* __restrict__ Bw,         // [400][2048]
    float* __restrict__ part)             // [4][4096][400]
{
    __shared__ bf16 As[64 * 36];          // pitch 36 bf16 = 72B: r15*18 mod 32 -> 16 distinct dwords
    __shared__ bf16 Bs[64 * 36];
    int tid = threadIdx.x;
    int m0 = blockIdx.x * 64, n0 = blockIdx.y * 64, ks = blockIdx.z;
    int row = tid >> 2, seg = tid & 3;
    int w = tid >> 6, lane = tid & 63, q = lane >> 4, r15 = lane & 15;
    f32x4 z4 = {0.f, 0.f, 0.f, 0.f};
    f32x4 acc[4] = {z4, z4, z4, z4};
    const float* pA = A + (size_t)(m0 + row) * 2048 + ks * 512 + seg * 8;
    bool bvalid = (n0 + row) < 400;
    const float* pB = Bw + (size_t)(n0 + row) * 2048 + ks * 512 + seg * 8;

    // prefetch tile 0 into registers
    f32x4 a0 = *(const f32x4*)pA;
    f32x4 a1 = *(const f32x4*)(pA + 4);
    f32x4 c0 = z4, c1 = z4;
    if (bvalid) { c0 = *(const f32x4*)pB; c1 = *(const f32x4*)(pB + 4); }

    for (int kt = 0; kt < 16; ++kt) {
        bf16x8 apk, bpk;
        apk[0] = (bf16)a0[0]; apk[1] = (bf16)a0[1]; apk[2] = (bf16)a0[2]; apk[3] = (bf16)a0[3];
        apk[4] = (bf16)a1[0]; apk[5] = (bf16)a1[1]; apk[6] = (bf16)a1[2]; apk[7] = (bf16)a1[3];
        bpk[0] = (bf16)c0[0]; bpk[1] = (bf16)c0[1]; bpk[2] = (bf16)c0[2]; bpk[3] = (bf16)c0[3];
        bpk[4] = (bf16)c1[0]; bpk[5] = (bf16)c1[1]; bpk[6] = (bf16)c1[2]; bpk[7] = (bf16)c1[3];
        __syncthreads();                              // prior compute done reading LDS
        *(bf16x8*)&As[row * 36 + seg * 8] = apk;
        *(bf16x8*)&Bs[row * 36 + seg * 8] = bpk;
        __syncthreads();
        if (kt < 15) {                                // issue next loads; overlap with MFMAs below
            pA += 32; pB += 32;
            a0 = *(const f32x4*)pA; a1 = *(const f32x4*)(pA + 4);
            if (bvalid) { c0 = *(const f32x4*)pB; c1 = *(const f32x4*)(pB + 4); }
        }
        bf16x8 a = *(const bf16x8*)&As[(w * 16 + r15) * 36 + q * 8];
#pragma unroll
        for (int nt = 0; nt < 4; ++nt) {
            bf16x8 bb = *(const bf16x8*)&Bs[(nt * 16 + r15) * 36 + q * 8];
            acc[nt] = __builtin_amdgcn_mfma_f32_16x16x32_bf16(a, bb, acc[nt], 0, 0, 0);
        }
    }
    float* pp = part + (size_t)ks * 1638400;
#pragma unroll
    for (int nt = 0; nt < 4; ++nt)
#pragma unroll
        for (int r = 0; r < 4; ++r) {
            int mm = m0 + w * 16 + q * 4 + r;
            int nn = n0 + nt * 16 + r15;
            if (nn < 400) pp[(size_t)mm * 400 + nn] = acc[nt][r];
        }
}

// ---------------- K6R: reduce 4 k-splits + bias + relu -> bf16 h1 ----------------
__global__ __launch_bounds__(256) void k6_reduce(
    const float* __restrict__ part,       // [4][4096][400]
    const float* __restrict__ bias,       // [400]
    bf16* __restrict__ h1)                // [4096][400]
{
    int i = blockIdx.x * 256 + threadIdx.x;           // 409600 f32x4 groups
    const f32x4* p = (const f32x4*)part;
    f32x4 s0 = p[i], s1v = p[i + 409600], s2v = p[i + 819200], s3v = p[i + 1228800];
    int nn = (i * 4) % 400;                           // 400 % 4 == 0: group stays in-row
    f32x4 bv = *(const f32x4*)&bias[nn];
    bf16x4 ov;
    ov[0] = (bf16)fmaxf(s0[0] + s1v[0] + s2v[0] + s3v[0] + bv[0], 0.f);
    ov[1] = (bf16)fmaxf(s0[1] + s1v[1] + s2v[1] + s3v[1] + bv[1], 0.f);
    ov[2] = (bf16)fmaxf(s0[2] + s1v[2] + s2v[2] + s3v[2] + bv[2], 0.f);
    ov[3] = (bf16)fmaxf(s0[3] + s1v[3] + s2v[3] + s3v[3] + bv[3], 0.f);
    *(bf16x4*)&h1[i * 4] = ov;
}

// ---------------- K7: MLP2  h2 = relu(h1 @ Wl2^T + bl2) ----------------
// 256 blocks, M=16 per block, A staged to LDS once, B streamed from regs, no K-loop barriers.
__global__ __launch_bounds__(256) void k7_mlp2(
    const bf16* __restrict__ A,           // [4096][400] bf16
    const float* __restrict__ Bw,         // [64][400] f32
    const float* __restrict__ bias,
    float* __restrict__ Cout)             // [4096][64]
{
    __shared__ bf16 As[16 * 416];         // K padded 400->416
    int tid = threadIdx.x;
    int m0 = blockIdx.x * 16;
    for (int i = tid; i < 16 * 50; i += 256) {        // 50 bf16x8 chunks per row
        int rr = i / 50, cc = (i % 50) * 8;
        *(bf16x8*)&As[rr * 416 + cc] = *(const bf16x8*)(A + (size_t)(m0 + rr) * 400 + cc);
    }
    if (tid < 32) {                                   // zero pad k = 400..415
        int rr = tid >> 1, cc = 400 + (tid & 1) * 8;
        bf16x8 z;
#pragma unroll
        for (int k = 0; k < 8; ++k) z[k] = (bf16)0.f;
        *(bf16x8*)&As[rr * 416 + cc] = z;
    }
    __syncthreads();

    int w = tid >> 6, lane = tid & 63, q = lane >> 4, r15 = lane & 15;
    f32x4 acc = {0.f, 0.f, 0.f, 0.f};
    const float* pB = Bw + (size_t)(w * 16 + r15) * 400;
#pragma unroll 4
    for (int kt = 0; kt < 13; ++kt) {
        int k0 = kt * 32 + q * 8;
        bf16x8 a = *(const bf16x8*)&As[r15 * 416 + k0];
        bf16x8 bb;
#pragma unroll
        for (int k = 0; k < 8; ++k) bb[k] = (bf16)0.f;
        if (k0 < 400) {
            f32x4 c0 = *(const f32x4*)(pB + k0);
            f32x4 c1 = *(const f32x4*)(pB + k0 + 4);
            bb[0] = (bf16)c0[0]; bb[1] = (bf16)c0[1]; bb[2] = (bf16)c0[2]; bb[3] = (bf16)c0[3];
            bb[4] = (bf16)c1[0]; bb[5] = (bf16)c1[1]; bb[6] = (bf16)c1[2]; bb[7] = (bf16)c1[3];
        }
        acc = __builtin_amdgcn_mfma_f32_16x16x32_bf16(a, bb, acc, 0, 0, 0);
    }
#pragma unroll
    for (int r = 0; r < 4; ++r) {
        int mm = m0 + q * 4 + r;
        int nn = w * 16 + r15;
        float v = fmaxf(acc[r] + bias[nn], 0.f);
        Cout[(size_t)mm * 64 + nn] = v;
    }
}

// ---------------- K8: BN2+relu+maxpool + concat + FC ----------------
__global__ __launch_bounds__(256) void k8_final(
    const bf16* __restrict__ g2out,       // [4096][64][32]
    const float* __restrict__ scale2, const float* __restrict__ shift2,
    const float* __restrict__ h2,         // [4096][64]
    const float* __restrict__ Wfc,        // [2][96]
    const float* __restrict__ bfc,
    float* __restrict__ out)              // [4096][2]
{
    __shared__ float s2s[64], sh2s[64];
    int tid = threadIdx.x;
    if (tid < 64) { s2s[tid] = scale2[tid]; sh2s[tid] = shift2[tid]; }
    __syncthreads();
    int w = tid >> 6, lane = tid & 63;
    int b = blockIdx.x * 4 + w;
    int c = lane & 31, half = lane >> 5;
    const bf16* gb = g2out + (size_t)b * 2048;
    float mx = 0.f;                                   // relu => max >= 0
    for (int i = 0; i < 32; ++i) {
        int n = half * 32 + i;
        float v = (float)gb[n * 32 + c];
        float val = fmaf(s2s[n], v, sh2s[n]);
        mx = fmaxf(mx, val);
    }
    mx = fmaxf(mx, __shfl_xor(mx, 32));               // pooled[c] on all lanes
    float h2v = h2[(size_t)b * 64 + lane];
#pragma unroll
    for (int o = 0; o < 2; ++o) {
        float t = h2v * Wfc[o * 96 + 32 + lane];
        if (half == 0) t += mx * Wfc[o * 96 + c];
#pragma unroll
        for (int off = 32; off > 0; off >>= 1) t += __shfl_xor(t, off);
        if (lane == 0) out[(size_t)b * 2 + o] = t + bfc[o];
    }
}

extern "C" void kernel_launch(void* const* d_in, const int* in_sizes, int n_in,
                              void* d_out, int out_size, void* d_ws, size_t ws_size,
                              hipStream_t stream)
{
    const float* x_fp   = (const float*)d_in[0];
    const float* x_node = (const float*)d_in[1];
    const int*   edge   = (const int*)d_in[2];
    const float* W1     = (const float*)d_in[3];
    const float* b1     = (const float*)d_in[4];
    const float* g1     = (const float*)d_in[5];
    const float* be1    = (const float*)d_in[6];
    const float* W2     = (const float*)d_in[7];
    const float* b2     = (const float*)d_in[8];
    const float* g2     = (const float*)d_in[9];
    const float* be2    = (const float*)d_in[10];
    const float* Wl1    = (const float*)d_in[11];
    const float* bl1    = (const float*)d_in[12];
    const float* Wl2    = (const float*)d_in[13];
    const float* bl2    = (const float*)d_in[14];
    const float* Wfc    = (const float*)d_in[15];
    const float* bfc    = (const float*)d_in[16];
    float* out = (float*)d_out;

    char* ws = (char*)d_ws;
    float* scale1  = (float*)(ws + 5632);
    float* shift1  = (float*)(ws + 5888);
    float* scale2  = (float*)(ws + 6144);
    float* shift2  = (float*)(ws + 6400);
    float* part1   = (float*)(ws + 8192);             // 65536 B
    float* part2   = (float*)(ws + 8192 + 65536);     // 65536 B
    bf16*  g1out   = (bf16*)(ws + 139264);            // 33554432 B (dead after k3 -> reused as part6)
    float* part6   = (float*)(ws + 139264);           // 26214400 B, overlays g1out
    bf16*  g2out   = (bf16*)(ws + 33693696ull);       // 16777216 B
    bf16*  h1      = (bf16*)(ws + 50470912ull);       // 3276800 B
    float* h2      = (float*)(ws + 53747712ull);      // 1048576 B
    // An + padded weight tables overlay the h2 region: written by k0, read by k1/k3,
    // dead before k7 writes h2 (stream-ordered, no overlap with h1/part6/g2out).
    bf16*  an_hi   = (bf16*)(ws + 53747712ull);               // 8192 B
    bf16*  an_lo   = (bf16*)(ws + 53747712ull + 8192);        // 8192 B
    bf16*  wpad    = (bf16*)(ws + 53747712ull + 16384);       // 13312 B
    bf16*  w2pad   = (bf16*)(ws + 53747712ull + 32768);       // 4608 B

    k0_prep<<<dim3(64), dim3(256), 0, stream>>>(edge, W1, W2, part1, an_hi, an_lo, wpad, w2pad);
    k1_gcn1<<<dim3(4096), dim3(256), 0, stream>>>(x_node, b1, an_hi, an_lo, wpad, g1out, part1);
    k_bnstats<<<dim3(64), dim3(64), 0, stream>>>(part1, g1, be1, scale1, shift1,
                                                 1.f / (4096.f * 64.f));
    k3_gcn2<<<dim3(4096), dim3(256), 0, stream>>>(g1out, b2, scale1, shift1,
                                                  an_hi, an_lo, w2pad, g2out, part2);
    k_bnstats<<<dim3(64), dim3(64), 0, stream>>>(part2, g2, be2, scale2, shift2,
                                                 1.f / (4096.f * 32.f));
    // g1out is dead now; k6 writes split-K partials into its space
    k6_mlp1<<<dim3(64, 7, 4), dim3(256), 0, stream>>>(x_fp, Wl1, part6);
    k6_reduce<<<dim3(1600), dim3(256), 0, stream>>>(part6, bl1, h1);
    k7_mlp2<<<dim3(256), dim3(256), 0, stream>>>(h1, Wl2, bl2, h2);
    k8_final<<<dim3(1024), dim3(256), 0, stream>>>(g2out, scale2, shift2, h2, Wfc, bfc, out);
}

// Round 2
// 241.346 us; speedup vs baseline: 1.1145x; 1.1145x over previous
//
#include <hip/hip_runtime.h>
#include <hip/hip_bf16.h>
#include <math.h>

typedef __bf16 bf16;
typedef __attribute__((ext_vector_type(8))) __bf16 bf16x8;
typedef __attribute__((ext_vector_type(4))) __bf16 bf16x4;
typedef __attribute__((ext_vector_type(4))) float f32x4;

#define EPSBN 1e-5f
#define B_    4096
#define N_    64
#define FIN_  67
#define E_    512
#define NSLOT 128

// ---------------- K0: dense normalized adjacency (bf16 hi/lo) + padded weights + zero partials ----
// An[d][s] = sum over edges (s->d, incl self loop, incl duplicates) of dinv[s]*dinv[d]
__global__ __launch_bounds__(256) void k0_prep(const int* __restrict__ edge,
    const float* __restrict__ W1, const float* __restrict__ W2,
    float* __restrict__ partials,          // NSLOT*64*2 * 2 layers, contiguous
    bf16* __restrict__ an_hi, bf16* __restrict__ an_lo,
    bf16* __restrict__ wpad,               // [64][104] bf16, K padded 67->104-pitch (zeros >=67)
    bf16* __restrict__ w2pad)              // [32][72]  bf16, K=64, pitch 72 (zeros >=64)
{
    int tid = threadIdx.x;
    for (int i = blockIdx.x * 256 + tid; i < NSLOT * 64 * 4; i += gridDim.x * 256)
        partials[i] = 0.f;
    if (blockIdx.x == 1) {
        for (int i = tid; i < 64 * 104; i += 256) {
            int n = i / 104, f = i % 104;
            wpad[i] = (f < FIN_) ? (bf16)W1[n * FIN_ + f] : (bf16)0.f;
        }
        return;
    }
    if (blockIdx.x == 2) {
        for (int i = tid; i < 32 * 72; i += 256) {
            int o = i / 72, f = i % 72;
            w2pad[i] = (f < 64) ? (bf16)W2[o * 64 + f] : (bf16)0.f;
        }
        return;
    }
    if (blockIdx.x != 0) return;

    __shared__ float An[64 * 64];
    __shared__ int ssrc[E_], sdst[E_];
    __shared__ int deg[N_];
    __shared__ float dinv[N_];
    for (int i = tid; i < 64 * 64; i += 256) An[i] = 0.f;
    for (int i = tid; i < E_; i += 256) { ssrc[i] = edge[i]; sdst[i] = edge[E_ + i]; }
    if (tid < N_) deg[tid] = 1;                       // self loop contributes 1
    __syncthreads();
    for (int i = tid; i < E_; i += 256) atomicAdd(&deg[sdst[i]], 1);
    __syncthreads();
    if (tid < N_) dinv[tid] = rsqrtf((float)deg[tid]);
    __syncthreads();
    for (int i = tid; i < E_; i += 256) {
        int s = ssrc[i], d = sdst[i];
        atomicAdd(&An[d * 64 + s], dinv[s] * dinv[d]);   // duplicates accumulate, like scatter-add
    }
    if (tid < N_) atomicAdd(&An[tid * 64 + tid], dinv[tid] * dinv[tid]);  // self loop
    __syncthreads();
    for (int i = tid; i < 64 * 64; i += 256) {
        float v = An[i];
        bf16 h = (bf16)v;
        an_hi[i] = h;
        an_lo[i] = (bf16)(v - (float)h);              // exact residual, bf16-rounded
    }
}

// ---------------- K1: GCN layer 1, 4 batches/block, reg-prefetch pipelined ----------------
// h = x@W1^T (MFMA, W1 frags in regs); out = An@h (MFMA, An frags in regs); bias+stats.
__global__ __launch_bounds__(256, 3) void k1_gcn1(
    const float* __restrict__ x,          // [B][64][67]
    const float* __restrict__ b1,
    const bf16* __restrict__ an_hi, const bf16* __restrict__ an_lo,
    const bf16* __restrict__ wpad,        // [64][104] bf16
    bf16* __restrict__ g1out,             // [B][64][64]
    float* __restrict__ part1)            // [NSLOT][64][2]
{
    __shared__ float xraw[4352];          // 17408 B, flat f32 copy of x[b]
    __shared__ bf16 hhi[64 * 72];         // 9216 B  hT hi
    __shared__ bf16 hlo[64 * 72];         // 9216 B  hT lo
    __shared__ bf16 ost[64 * 72];         // 9216 B  output staging (row-major, pitch 72)

    int tid = threadIdx.x;
    int w = tid >> 6, lane = tid & 63, q = lane >> 4, r15 = lane & 15;
    int arow = w * 16 + r15;

    // W1 fragments in registers (same bytes for every block -> L2-hot)
    bf16x8 wf[3][4];
#pragma unroll
    for (int kt = 0; kt < 3; ++kt)
#pragma unroll
        for (int nt = 0; nt < 4; ++nt)
            wf[kt][nt] = *(const bf16x8*)&wpad[(nt * 16 + r15) * 104 + kt * 32 + q * 8];

    const bf16* ahp = an_hi + arow * 64 + q * 8;
    const bf16* alp = an_lo + arow * 64 + q * 8;
    bf16x8 Ah0 = *(const bf16x8*)ahp;
    bf16x8 Ah1 = *(const bf16x8*)(ahp + 32);
    bf16x8 Al0 = *(const bf16x8*)alp;
    bf16x8 Al1 = *(const bf16x8*)(alp + 32);

    float bc[4];
#pragma unroll
    for (int nt = 0; nt < 4; ++nt) bc[nt] = b1[nt * 16 + r15];

    size_t b0 = (size_t)blockIdx.x * 4;
    const f32x4* xb4 = (const f32x4*)(x + b0 * 4288);   // 1072 chunks per batch

    // prefetch batch 0 into registers
    f32x4 pre0 = xb4[tid], pre1 = xb4[tid + 256], pre2 = xb4[tid + 512], pre3 = xb4[tid + 768];
    f32x4 pre4 = {0.f, 0.f, 0.f, 0.f};
    if (tid < 48) pre4 = xb4[tid + 1024];

    f32x4* xl4 = (f32x4*)xraw;
    f32x4 z4 = {0.f, 0.f, 0.f, 0.f};

#pragma unroll 1
    for (int g = 0; g < 4; ++g) {
        int b = (int)b0 + g;
        // regs -> LDS
        xl4[tid] = pre0; xl4[tid + 256] = pre1; xl4[tid + 512] = pre2; xl4[tid + 768] = pre3;
        if (tid < 48) xl4[tid + 1024] = pre4;
        __syncthreads();                              // B1: xraw ready

        // MFMA1: h[n][c] = sum_k x[n][k]*W1[c][k]
        f32x4 acc[4] = {z4, z4, z4, z4};
        const float* xr = xraw + arow * FIN_;
#pragma unroll
        for (int kt = 0; kt < 3; ++kt) {
            bf16x8 a;
            if (kt < 2) {
                int k0 = kt * 32 + q * 8;
#pragma unroll
                for (int j = 0; j < 8; ++j) a[j] = (bf16)xr[k0 + j];
            } else {
#pragma unroll
                for (int j = 0; j < 8; ++j) a[j] = (bf16)0.f;
                if (q == 0) { a[0] = (bf16)xr[64]; a[1] = (bf16)xr[65]; a[2] = (bf16)xr[66]; }
            }
#pragma unroll
            for (int nt = 0; nt < 4; ++nt)
                acc[nt] = __builtin_amdgcn_mfma_f32_16x16x32_bf16(a, wf[kt][nt], acc[nt], 0, 0, 0);
        }
        // issue next batch's loads (register-destined: not drained by barriers)
        if (g < 3) {
            const f32x4* xn = xb4 + (size_t)(g + 1) * 1072;
            pre0 = xn[tid]; pre1 = xn[tid + 256]; pre2 = xn[tid + 512]; pre3 = xn[tid + 768];
            if (tid < 48) pre4 = xn[tid + 1024];
        }
        __syncthreads();                              // B2: xraw reads done

        // write h^T hi/lo
        int sbase = w * 16 + q * 4;
#pragma unroll
        for (int nt = 0; nt < 4; ++nt) {
            int c = nt * 16 + r15;
            bf16x4 hi, lo;
#pragma unroll
            for (int r = 0; r < 4; ++r) {
                float v = acc[nt][r];
                bf16 h = (bf16)v;
                hi[r] = h; lo[r] = (bf16)(v - (float)h);
            }
            *(bf16x4*)&hhi[c * 72 + sbase] = hi;
            *(bf16x4*)&hlo[c * 72 + sbase] = lo;
        }
        __syncthreads();                              // B3: hT ready

        // MFMA2: out[d][c] = An_hi@(Hh+Hl) + An_lo@Hh
        f32x4 acc2[4] = {z4, z4, z4, z4};
#pragma unroll
        for (int kt = 0; kt < 2; ++kt) {
            bf16x8 Ahk = kt ? Ah1 : Ah0;
            bf16x8 Alk = kt ? Al1 : Al0;
#pragma unroll
            for (int nt = 0; nt < 4; ++nt) {
                int o = (nt * 16 + r15) * 72 + kt * 32 + q * 8;
                bf16x8 Hh = *(const bf16x8*)&hhi[o];
                bf16x8 Hl = *(const bf16x8*)&hlo[o];
                acc2[nt] = __builtin_amdgcn_mfma_f32_16x16x32_bf16(Ahk, Hh, acc2[nt], 0, 0, 0);
                acc2[nt] = __builtin_amdgcn_mfma_f32_16x16x32_bf16(Ahk, Hl, acc2[nt], 0, 0, 0);
                acc2[nt] = __builtin_amdgcn_mfma_f32_16x16x32_bf16(Alk, Hh, acc2[nt], 0, 0, 0);
            }
        }
        // bias + stage output rows (separate buffer: no overlay hazard)
#pragma unroll
        for (int nt = 0; nt < 4; ++nt) {
            int c = nt * 16 + r15;
#pragma unroll
            for (int r = 0; r < 4; ++r)
                ost[(sbase + r) * 72 + c] = (bf16)(acc2[nt][r] + bc[nt]);
        }
        __syncthreads();                              // B4: ost ready

        // coalesced store + stats from the stored bf16 values (consistent with k3's input)
        int n = tid >> 2, oq = tid & 3;
        bf16x8 o0 = *(const bf16x8*)&ost[n * 72 + oq * 16];
        bf16x8 o1 = *(const bf16x8*)&ost[n * 72 + oq * 16 + 8];
        bf16* gp = g1out + ((size_t)b * 4096 + n * 64 + oq * 16);
        *(bf16x8*)gp = o0;
        *(bf16x8*)(gp + 8) = o1;
        float s1 = 0.f, s2 = 0.f;
#pragma unroll
        for (int j = 0; j < 8; ++j) {
            float v0 = (float)o0[j], v1 = (float)o1[j];
            s1 += v0 + v1; s2 += v0 * v0 + v1 * v1;
        }
        s1 += __shfl_xor(s1, 1); s1 += __shfl_xor(s1, 2);
        s2 += __shfl_xor(s2, 1); s2 += __shfl_xor(s2, 2);
        if (oq == 0) {
            int slot = b & (NSLOT - 1);
            atomicAdd(&part1[(slot * 64 + n) * 2 + 0], s1);
            atomicAdd(&part1[(slot * 64 + n) * 2 + 1], s2);
        }
        // no trailing barrier: next iter's first conflicting LDS write is gated by its B1/B2/B3
    }
}

// ---------------- BN stats reduce: partials -> scale/shift per node ----------------
__global__ __launch_bounds__(64) void k_bnstats(
    const float* __restrict__ part,       // [NSLOT][64][2]
    const float* __restrict__ gamma, const float* __restrict__ beta,
    float* __restrict__ scale, float* __restrict__ shift, float inv_count)
{
    int n = blockIdx.x, t = threadIdx.x;
    float s1 = part[(t * 64 + n) * 2] + part[((t + 64) * 64 + n) * 2];
    float s2 = part[(t * 64 + n) * 2 + 1] + part[((t + 64) * 64 + n) * 2 + 1];
#pragma unroll
    for (int o = 32; o > 0; o >>= 1) { s1 += __shfl_down(s1, o); s2 += __shfl_down(s2, o); }
    if (t == 0) {
        float mean = s1 * inv_count;
        float var = s2 * inv_count - mean * mean;
        float sc = gamma[n] * rsqrtf(var + EPSBN);
        scale[n] = sc;
        shift[n] = beta[n] - mean * sc;
    }
}

// ---------------- K3: BN1+relu fused -> GCN layer 2, 4 batches/block pipelined ----------------
__global__ __launch_bounds__(256, 4) void k3_gcn2(
    const bf16* __restrict__ g1out,       // [B][64][64]
    const float* __restrict__ b2,
    const float* __restrict__ scale1, const float* __restrict__ shift1,
    const bf16* __restrict__ an_hi, const bf16* __restrict__ an_lo,
    const bf16* __restrict__ w2pad,       // [32][72] bf16
    bf16* __restrict__ g2out,             // [B][64][32]
    float* __restrict__ part2)
{
    __shared__ bf16 ya[64 * 72];          // raw g1 tile, pitch 72 (16-way-conflict fix vs pitch 64)
    __shared__ bf16 hhi[32 * 72];
    __shared__ bf16 hlo[32 * 72];
    __shared__ bf16 ost[64 * 40];

    int tid = threadIdx.x;
    int w = tid >> 6, lane = tid & 63, q = lane >> 4, r15 = lane & 15;
    int arow = w * 16 + r15;

    bf16x8 wf[2][2];
#pragma unroll
    for (int kt = 0; kt < 2; ++kt)
#pragma unroll
        for (int nt = 0; nt < 2; ++nt)
            wf[kt][nt] = *(const bf16x8*)&w2pad[(nt * 16 + r15) * 72 + kt * 32 + q * 8];

    const bf16* ahp = an_hi + arow * 64 + q * 8;
    const bf16* alp = an_lo + arow * 64 + q * 8;
    bf16x8 Ah0 = *(const bf16x8*)ahp;
    bf16x8 Ah1 = *(const bf16x8*)(ahp + 32);
    bf16x8 Al0 = *(const bf16x8*)alp;
    bf16x8 Al1 = *(const bf16x8*)(alp + 32);
    float sc = scale1[arow], sh = shift1[arow];
    float bc[2] = { b2[r15], b2[16 + r15] };

    size_t b0 = (size_t)blockIdx.x * 4;
    const bf16x8* gg8 = (const bf16x8*)(g1out + b0 * 4096);   // 512 chunks per batch
    bf16x8 p0 = gg8[tid], p1 = gg8[tid + 256];

    int r0 = tid >> 3, c0 = (tid & 7) * 8;            // staging coords (pitch 72)
    f32x4 z4 = {0.f, 0.f, 0.f, 0.f};

#pragma unroll 1
    for (int g = 0; g < 4; ++g) {
        int b = (int)b0 + g;
        *(bf16x8*)&ya[r0 * 72 + c0] = p0;
        *(bf16x8*)&ya[(r0 + 32) * 72 + c0] = p1;
        __syncthreads();                              // B1

        // MFMA1: h[n][o] = sum_c relu(sc[n]*g1[n][c]+sh[n]) * W2[o][c]
        f32x4 acc[2] = {z4, z4};
#pragma unroll
        for (int kt = 0; kt < 2; ++kt) {
            int k0 = kt * 32 + q * 8;
            bf16x8 raw = *(const bf16x8*)&ya[arow * 72 + k0];
            bf16x8 a;
#pragma unroll
            for (int j = 0; j < 8; ++j)
                a[j] = (bf16)fmaxf(fmaf(sc, (float)raw[j], sh), 0.f);
#pragma unroll
            for (int nt = 0; nt < 2; ++nt)
                acc[nt] = __builtin_amdgcn_mfma_f32_16x16x32_bf16(a, wf[kt][nt], acc[nt], 0, 0, 0);
        }
        if (g < 3) {
            p0 = gg8[(size_t)(g + 1) * 512 + tid];
            p1 = gg8[(size_t)(g + 1) * 512 + tid + 256];
        }
        __syncthreads();                              // B2

        int sbase = w * 16 + q * 4;
#pragma unroll
        for (int nt = 0; nt < 2; ++nt) {
            int c = nt * 16 + r15;
            bf16x4 hi, lo;
#pragma unroll
            for (int r = 0; r < 4; ++r) {
                float v = acc[nt][r];
                bf16 h = (bf16)v;
                hi[r] = h; lo[r] = (bf16)(v - (float)h);
            }
            *(bf16x4*)&hhi[c * 72 + sbase] = hi;
            *(bf16x4*)&hlo[c * 72 + sbase] = lo;
        }
        __syncthreads();                              // B3

        f32x4 acc2[2] = {z4, z4};
#pragma unroll
        for (int kt = 0; kt < 2; ++kt) {
            bf16x8 Ahk = kt ? Ah1 : Ah0;
            bf16x8 Alk = kt ? Al1 : Al0;
#pragma unroll
            for (int nt = 0; nt < 2; ++nt) {
                int o = (nt * 16 + r15) * 72 + kt * 32 + q * 8;
                bf16x8 Hh = *(const bf16x8*)&hhi[o];
                bf16x8 Hl = *(const bf16x8*)&hlo[o];
                acc2[nt] = __builtin_amdgcn_mfma_f32_16x16x32_bf16(Ahk, Hh, acc2[nt], 0, 0, 0);
                acc2[nt] = __builtin_amdgcn_mfma_f32_16x16x32_bf16(Ahk, Hl, acc2[nt], 0, 0, 0);
                acc2[nt] = __builtin_amdgcn_mfma_f32_16x16x32_bf16(Alk, Hh, acc2[nt], 0, 0, 0);
            }
        }
#pragma unroll
        for (int nt = 0; nt < 2; ++nt) {
            int c = nt * 16 + r15;
#pragma unroll
            for (int r = 0; r < 4; ++r)
                ost[(sbase + r) * 40 + c] = (bf16)(acc2[nt][r] + bc[nt]);
        }
        __syncthreads();                              // B4

        int n = tid >> 2, oq = tid & 3;
        bf16x8 ov = *(const bf16x8*)&ost[n * 40 + oq * 8];
        *(bf16x8*)(g2out + ((size_t)b * 2048 + n * 32 + oq * 8)) = ov;
        float s1 = 0.f, s2 = 0.f;
#pragma unroll
        for (int j = 0; j < 8; ++j) {
            float v = (float)ov[j];
            s1 += v; s2 += v * v;
        }
        s1 += __shfl_xor(s1, 1); s1 += __shfl_xor(s1, 2);
        s2 += __shfl_xor(s2, 1); s2 += __shfl_xor(s2, 2);
        if (oq == 0) {
            int slot = b & (NSLOT - 1);
            atomicAdd(&part2[(slot * 64 + n) * 2 + 0], s1);
            atomicAdd(&part2[(slot * 64 + n) * 2 + 1], s2);
        }
    }
}

// ---------------- K6: MLP1 split-K GEMM, register-prefetch pipeline ----------------
// grid (64 m-tiles, 7 n-tiles, 4 k-splits) = 1792 blocks; partials fp32.
__global__ __launch_bounds__(256) void k6_mlp1(
    const float* __restrict__ A,          // [4096][2048]
    const float* __restrict__ Bw,         // [400][2048]
    float* __restrict__ part)             // [4][4096][400]
{
    __shared__ bf16 As[64 * 36];          // pitch 36 bf16 = 72B
    __shared__ bf16 Bs[64 * 36];
    int tid = threadIdx.x;
    int m0 = blockIdx.x * 64, n0 = blockIdx.y * 64, ks = blockIdx.z;
    int row = tid >> 2, seg = tid & 3;
    int w = tid >> 6, lane = tid & 63, q = lane >> 4, r15 = lane & 15;
    f32x4 z4 = {0.f, 0.f, 0.f, 0.f};
    f32x4 acc[4] = {z4, z4, z4, z4};
    const float* pA = A + (size_t)(m0 + row) * 2048 + ks * 512 + seg * 8;
    bool bvalid = (n0 + row) < 400;
    const float* pB = Bw + (size_t)(n0 + row) * 2048 + ks * 512 + seg * 8;

    f32x4 a0 = *(const f32x4*)pA;
    f32x4 a1 = *(const f32x4*)(pA + 4);
    f32x4 c0 = z4, c1 = z4;
    if (bvalid) { c0 = *(const f32x4*)pB; c1 = *(const f32x4*)(pB + 4); }

    for (int kt = 0; kt < 16; ++kt) {
        bf16x8 apk, bpk;
        apk[0] = (bf16)a0[0]; apk[1] = (bf16)a0[1]; apk[2] = (bf16)a0[2]; apk[3] = (bf16)a0[3];
        apk[4] = (bf16)a1[0]; apk[5] = (bf16)a1[1]; apk[6] = (bf16)a1[2]; apk[7] = (bf16)a1[3];
        bpk[0] = (bf16)c0[0]; bpk[1] = (bf16)c0[1]; bpk[2] = (bf16)c0[2]; bpk[3] = (bf16)c0[3];
        bpk[4] = (bf16)c1[0]; bpk[5] = (bf16)c1[1]; bpk[6] = (bf16)c1[2]; bpk[7] = (bf16)c1[3];
        __syncthreads();
        *(bf16x8*)&As[row * 36 + seg * 8] = apk;
        *(bf16x8*)&Bs[row * 36 + seg * 8] = bpk;
        __syncthreads();
        if (kt < 15) {
            pA += 32; pB += 32;
            a0 = *(const f32x4*)pA; a1 = *(const f32x4*)(pA + 4);
            if (bvalid) { c0 = *(const f32x4*)pB; c1 = *(const f32x4*)(pB + 4); }
        }
        bf16x8 a = *(const bf16x8*)&As[(w * 16 + r15) * 36 + q * 8];
#pragma unroll
        for (int nt = 0; nt < 4; ++nt) {
            bf16x8 bb = *(const bf16x8*)&Bs[(nt * 16 + r15) * 36 + q * 8];
            acc[nt] = __builtin_amdgcn_mfma_f32_16x16x32_bf16(a, bb, acc[nt], 0, 0, 0);
        }
    }
    float* pp = part + (size_t)ks * 1638400;
#pragma unroll
    for (int nt = 0; nt < 4; ++nt)
#pragma unroll
        for (int r = 0; r < 4; ++r) {
            int mm = m0 + w * 16 + q * 4 + r;
            int nn = n0 + nt * 16 + r15;
            if (nn < 400) pp[(size_t)mm * 400 + nn] = acc[nt][r];
        }
}

// ---------------- K6R: reduce 4 k-splits + bias + relu -> bf16 h1 ----------------
__global__ __launch_bounds__(256) void k6_reduce(
    const float* __restrict__ part,       // [4][4096][400]
    const float* __restrict__ bias,       // [400]
    bf16* __restrict__ h1)                // [4096][400]
{
    int i = blockIdx.x * 256 + threadIdx.x;           // 409600 f32x4 groups
    const f32x4* p = (const f32x4*)part;
    f32x4 s0 = p[i], s1v = p[i + 409600], s2v = p[i + 819200], s3v = p[i + 1228800];
    int nn = (i * 4) % 400;
    f32x4 bv = *(const f32x4*)&bias[nn];
    bf16x4 ov;
    ov[0] = (bf16)fmaxf(s0[0] + s1v[0] + s2v[0] + s3v[0] + bv[0], 0.f);
    ov[1] = (bf16)fmaxf(s0[1] + s1v[1] + s2v[1] + s3v[1] + bv[1], 0.f);
    ov[2] = (bf16)fmaxf(s0[2] + s1v[2] + s2v[2] + s3v[2] + bv[2], 0.f);
    ov[3] = (bf16)fmaxf(s0[3] + s1v[3] + s2v[3] + s3v[3] + bv[3], 0.f);
    *(bf16x4*)&h1[i * 4] = ov;
}

// ---------------- K7: MLP2  h2 = relu(h1 @ Wl2^T + bl2) ----------------
__global__ __launch_bounds__(256) void k7_mlp2(
    const bf16* __restrict__ A,           // [4096][400] bf16
    const float* __restrict__ Bw,         // [64][400] f32
    const float* __restrict__ bias,
    float* __restrict__ Cout)             // [4096][64]
{
    __shared__ bf16 As[16 * 416];         // K padded 400->416
    int tid = threadIdx.x;
    int m0 = blockIdx.x * 16;
    for (int i = tid; i < 16 * 50; i += 256) {
        int rr = i / 50, cc = (i % 50) * 8;
        *(bf16x8*)&As[rr * 416 + cc] = *(const bf16x8*)(A + (size_t)(m0 + rr) * 400 + cc);
    }
    if (tid < 32) {
        int rr = tid >> 1, cc = 400 + (tid & 1) * 8;
        bf16x8 z;
#pragma unroll
        for (int k = 0; k < 8; ++k) z[k] = (bf16)0.f;
        *(bf16x8*)&As[rr * 416 + cc] = z;
    }
    __syncthreads();

    int w = tid >> 6, lane = tid & 63, q = lane >> 4, r15 = lane & 15;
    f32x4 acc = {0.f, 0.f, 0.f, 0.f};
    const float* pB = Bw + (size_t)(w * 16 + r15) * 400;
#pragma unroll 4
    for (int kt = 0; kt < 13; ++kt) {
        int k0 = kt * 32 + q * 8;
        bf16x8 a = *(const bf16x8*)&As[r15 * 416 + k0];
        bf16x8 bb;
#pragma unroll
        for (int k = 0; k < 8; ++k) bb[k] = (bf16)0.f;
        if (k0 < 400) {
            f32x4 c0 = *(const f32x4*)(pB + k0);
            f32x4 c1 = *(const f32x4*)(pB + k0 + 4);
            bb[0] = (bf16)c0[0]; bb[1] = (bf16)c0[1]; bb[2] = (bf16)c0[2]; bb[3] = (bf16)c0[3];
            bb[4] = (bf16)c1[0]; bb[5] = (bf16)c1[1]; bb[6] = (bf16)c1[2]; bb[7] = (bf16)c1[3];
        }
        acc = __builtin_amdgcn_mfma_f32_16x16x32_bf16(a, bb, acc, 0, 0, 0);
    }
#pragma unroll
    for (int r = 0; r < 4; ++r) {
        int mm = m0 + q * 4 + r;
        int nn = w * 16 + r15;
        float v = fmaxf(acc[r] + bias[nn], 0.f);
        Cout[(size_t)mm * 64 + nn] = v;
    }
}

// ---------------- K8: BN2+relu+maxpool + concat + FC ----------------
__global__ __launch_bounds__(256) void k8_final(
    const bf16* __restrict__ g2out,       // [4096][64][32]
    const float* __restrict__ scale2, const float* __restrict__ shift2,
    const float* __restrict__ h2,         // [4096][64]
    const float* __restrict__ Wfc,        // [2][96]
    const float* __restrict__ bfc,
    float* __restrict__ out)              // [4096][2]
{
    __shared__ float s2s[64], sh2s[64];
    int tid = threadIdx.x;
    if (tid < 64) { s2s[tid] = scale2[tid]; sh2s[tid] = shift2[tid]; }
    __syncthreads();
    int w = tid >> 6, lane = tid & 63;
    int b = blockIdx.x * 4 + w;
    int c = lane & 31, half = lane >> 5;
    const bf16* gb = g2out + (size_t)b * 2048;
    float mx = 0.f;
    for (int i = 0; i < 32; ++i) {
        int n = half * 32 + i;
        float v = (float)gb[n * 32 + c];
        float val = fmaf(s2s[n], v, sh2s[n]);
        mx = fmaxf(mx, val);
    }
    mx = fmaxf(mx, __shfl_xor(mx, 32));
    float h2v = h2[(size_t)b * 64 + lane];
#pragma unroll
    for (int o = 0; o < 2; ++o) {
        float t = h2v * Wfc[o * 96 + 32 + lane];
        if (half == 0) t += mx * Wfc[o * 96 + c];
#pragma unroll
        for (int off = 32; off > 0; off >>= 1) t += __shfl_xor(t, off);
        if (lane == 0) out[(size_t)b * 2 + o] = t + bfc[o];
    }
}

extern "C" void kernel_launch(void* const* d_in, const int* in_sizes, int n_in,
                              void* d_out, int out_size, void* d_ws, size_t ws_size,
                              hipStream_t stream)
{
    const float* x_fp   = (const float*)d_in[0];
    const float* x_node = (const float*)d_in[1];
    const int*   edge   = (const int*)d_in[2];
    const float* W1     = (const float*)d_in[3];
    const float* b1     = (const float*)d_in[4];
    const float* g1     = (const float*)d_in[5];
    const float* be1    = (const float*)d_in[6];
    const float* W2     = (const float*)d_in[7];
    const float* b2     = (const float*)d_in[8];
    const float* g2     = (const float*)d_in[9];
    const float* be2    = (const float*)d_in[10];
    const float* Wl1    = (const float*)d_in[11];
    const float* bl1    = (const float*)d_in[12];
    const float* Wl2    = (const float*)d_in[13];
    const float* bl2    = (const float*)d_in[14];
    const float* Wfc    = (const float*)d_in[15];
    const float* bfc    = (const float*)d_in[16];
    float* out = (float*)d_out;

    char* ws = (char*)d_ws;
    float* scale1  = (float*)(ws + 5632);
    float* shift1  = (float*)(ws + 5888);
    float* scale2  = (float*)(ws + 6144);
    float* shift2  = (float*)(ws + 6400);
    float* part1   = (float*)(ws + 8192);             // 65536 B
    float* part2   = (float*)(ws + 8192 + 65536);     // 65536 B
    bf16*  g1out   = (bf16*)(ws + 139264);            // 33554432 B (dead after k3 -> reused as part6)
    float* part6   = (float*)(ws + 139264);           // 26214400 B, overlays g1out
    bf16*  g2out   = (bf16*)(ws + 33693696ull);       // 16777216 B
    bf16*  h1      = (bf16*)(ws + 50470912ull);       // 3276800 B
    float* h2      = (float*)(ws + 53747712ull);      // 1048576 B
    // An + padded weight tables overlay the h2 region: written by k0, read by k1/k3,
    // dead before k7 writes h2 (stream-ordered, no overlap with h1/part6/g2out).
    bf16*  an_hi   = (bf16*)(ws + 53747712ull);               // 8192 B
    bf16*  an_lo   = (bf16*)(ws + 53747712ull + 8192);        // 8192 B
    bf16*  wpad    = (bf16*)(ws + 53747712ull + 16384);       // 13312 B
    bf16*  w2pad   = (bf16*)(ws + 53747712ull + 32768);       // 4608 B

    k0_prep<<<dim3(64), dim3(256), 0, stream>>>(edge, W1, W2, part1, an_hi, an_lo, wpad, w2pad);
    k1_gcn1<<<dim3(1024), dim3(256), 0, stream>>>(x_node, b1, an_hi, an_lo, wpad, g1out, part1);
    k_bnstats<<<dim3(64), dim3(64), 0, stream>>>(part1, g1, be1, scale1, shift1,
                                                 1.f / (4096.f * 64.f));
    k3_gcn2<<<dim3(1024), dim3(256), 0, stream>>>(g1out, b2, scale1, shift1,
                                                  an_hi, an_lo, w2pad, g2out, part2);
    k_bnstats<<<dim3(64), dim3(64), 0, stream>>>(part2, g2, be2, scale2, shift2,
                                                 1.f / (4096.f * 32.f));
    // g1out is dead now; k6 writes split-K partials into its space
    k6_mlp1<<<dim3(64, 7, 4), dim3(256), 0, stream>>>(x_fp, Wl1, part6);
    k6_reduce<<<dim3(1600), dim3(256), 0, stream>>>(part6, bl1, h1);
    k7_mlp2<<<dim3(256), dim3(256), 0, stream>>>(h1, Wl2, bl2, h2);
    k8_final<<<dim3(1024), dim3(256), 0, stream>>>(g2out, scale2, shift2, h2, Wfc, bfc, out);
}